// Round 6
// baseline (118.492 us; speedup 1.0000x reference)
//
#include <hip/hip_runtime.h>

#define NUM_PRIORS 65536
#define BATCH 8
#define GNUM 64
#define NBLK 256
#define GPB 8      // GTs per block in kernel A
#define NCHUNK 32  // prior chunks; 65536/32 = 2048 priors per block
#define PPT 8      // priors per thread in kernel A = 2048/256

typedef unsigned long long u64;
typedef unsigned int u32;

// ---------------------------------------------------------------------------
// Strict, non-fusable fp32 ops: explicit ISA instructions. Inline asm cannot
// be pattern-matched into v_fmac/v_fma by the compiler, so the IoU chain is
// bit-identical to numpy's per-op strict float32 regardless of codegen
// context. (R2 passed / R3 failed with identical source math — contraction
// of area/inter products into FMAs flipped one razor-edge argmax. HIP's
// __f*_rn intrinsics did NOT inhibit contraction — R4 evidence.)
// ---------------------------------------------------------------------------
__device__ inline float vmulf(float a, float b) {
    float r; asm("v_mul_f32 %0, %1, %2" : "=v"(r) : "v"(a), "v"(b)); return r;
}
__device__ inline float vaddf(float a, float b) {
    float r; asm("v_add_f32 %0, %1, %2" : "=v"(r) : "v"(a), "v"(b)); return r;
}
__device__ inline float vsubf(float a, float b) {
    float r; asm("v_sub_f32 %0, %1, %2" : "=v"(r) : "v"(a), "v"(b)); return r;
}

__device__ inline float area_ref(const float4 bx) {
    return vmulf(vsubf(bx.z, bx.x), vsubf(bx.w, bx.y));
}

// ref op order: lt=max, rb=min, wh=max(rb-lt,0), inter=w*h,
// denom=(areaA+areaB)-inter, iou=inter/denom (IEEE divide).
__device__ inline float iou_ref(const float4 pr, float area_p,
                                const float4 gb, float area_g) {
    const float ltx = fmaxf(pr.x, gb.x);
    const float lty = fmaxf(pr.y, gb.y);
    const float rbx = fminf(pr.z, gb.z);
    const float rby = fminf(pr.w, gb.w);
    const float w = fmaxf(vsubf(rbx, ltx), 0.0f);
    const float h = fmaxf(vsubf(rby, lty), 0.0f);
    const float inter = vmulf(w, h);
    const float denom = vsubf(vaddf(area_p, area_g), inter);
    return inter / denom;  // IEEE-correct without fast-math
}

__device__ inline u64 shfl_down_u64(u64 x, int off) {
    u32 lo = (u32)x, hi = (u32)(x >> 32);
    lo = __shfl_down(lo, off);
    hi = __shfl_down(hi, off);
    return ((u64)hi << 32) | lo;
}

// ---------------------------------------------------------------------------
// Kernel A: per (b, g, chunk) partial argmax over 2048 priors of IoU.
// Packed key (iou_bits<<32 | ~p): IoU >= 0 so fp32 bits are monotone as u32;
// ~p makes equal-IoU ties resolve to smallest p (argmax first-occurrence).
// Plain stores to partials — fully written, no pre-zeroing, no atomics.
// ---------------------------------------------------------------------------
__global__ __launch_bounds__(NBLK) void best_prior_partial(
    const float* __restrict__ priors,    // [P,4] corner
    const float* __restrict__ gt_boxes,  // [B,G,4] corner
    u64* __restrict__ partials)          // [B][G][NCHUNK]
{
    const int b = blockIdx.z;
    const int g0 = blockIdx.y * GPB;
    const int tid = threadIdx.x;

    float4 gb[GPB];
    float ag[GPB];
#pragma unroll
    for (int g = 0; g < GPB; ++g) {
        gb[g] = *reinterpret_cast<const float4*>(gt_boxes + (b * GNUM + g0 + g) * 4);
        ag[g] = area_ref(gb[g]);
    }

    u64 best[GPB];
#pragma unroll
    for (int g = 0; g < GPB; ++g) best[g] = 0ull;

    const int pbase = blockIdx.x * (NUM_PRIORS / NCHUNK) + tid;
#pragma unroll
    for (int i = 0; i < PPT; ++i) {
        const int p = pbase + i * NBLK;
        const float4 pr = *reinterpret_cast<const float4*>(priors + p * 4);
        const float area_p = area_ref(pr);
        const u64 notp = (u64)(~(u32)p);
#pragma unroll
        for (int g = 0; g < GPB; ++g) {
            const float iou = iou_ref(pr, area_p, gb[g], ag[g]);
            const u64 packed = ((u64)__float_as_uint(iou) << 32) | notp;
            best[g] = (packed > best[g]) ? packed : best[g];
        }
    }

    __shared__ u64 sRed[NBLK / 64][GPB];
    const int lane = tid & 63;
    const int wv = tid >> 6;
#pragma unroll
    for (int g = 0; g < GPB; ++g) {
        u64 v = best[g];
#pragma unroll
        for (int off = 32; off > 0; off >>= 1) {
            const u64 o = shfl_down_u64(v, off);
            v = (o > v) ? o : v;
        }
        if (lane == 0) sRed[wv][g] = v;
    }
    __syncthreads();
    if (tid < GPB) {
        u64 v = sRed[0][tid];
#pragma unroll
        for (int w = 1; w < NBLK / 64; ++w) {
            const u64 o = sRed[w][tid];
            v = (o > v) ? o : v;
        }
        partials[((size_t)b * GNUM + g0 + tid) * NCHUNK + blockIdx.x] = v;
    }
}

// ---------------------------------------------------------------------------
// Kernel B: per (b, p): fold partials -> best prior per GT; strict-f32 argmax
// over g (first occurrence); override (last-g-wins, numpy duplicate-scatter);
// 0.5 threshold on the same strict-f32 iou; SSD encode; write loc + conf.
// ---------------------------------------------------------------------------
__global__ __launch_bounds__(NBLK) void match_kernel(
    const float* __restrict__ priors,    // [P,4]
    const float* __restrict__ gt_boxes,  // [B,G,4]
    const int* __restrict__ gt_labels,   // [B,G]
    const u64* __restrict__ partials,    // [B][G][NCHUNK]
    float* __restrict__ out)             // loc [B,P,4] then conf [B,P]
{
    const int b = blockIdx.y;
    const int p = blockIdx.x * NBLK + threadIdx.x;
    const int tid = threadIdx.x;

    __shared__ float4 sGT[GNUM];
    __shared__ float sAG[GNUM];
    __shared__ int sLab[GNUM];
    __shared__ int sBpi[GNUM];
    if (tid < GNUM) {
        const float4 gbx = *reinterpret_cast<const float4*>(
            gt_boxes + (b * GNUM + tid) * 4);
        sGT[tid] = gbx;
        sAG[tid] = area_ref(gbx);
        sLab[tid] = gt_labels[b * GNUM + tid];
        const u64* pp = partials + ((size_t)b * GNUM + tid) * NCHUNK;
        u64 v = pp[0];
#pragma unroll
        for (int c = 1; c < NCHUNK; ++c) {
            const u64 o = pp[c];
            v = (o > v) ? o : v;
        }
        sBpi[tid] = (int)(~(u32)v);
    }
    __syncthreads();

    const float4 pr = *reinterpret_cast<const float4*>(priors + p * 4);
    const float area_p = area_ref(pr);

    float best = -1.0f;
    int bg = 0;
    int ovr = -1;
    for (int g = 0; g < GNUM; ++g) {
        const float iou = iou_ref(pr, area_p, sGT[g], sAG[g]);
        if (iou > best) { best = iou; bg = g; }   // strict > = first occurrence
        if (sBpi[g] == p) ovr = g;                // ascending g = last-wins
    }

    int gi = bg;
    float biou = best;
    if (ovr >= 0) { gi = ovr; biou = 2.0f; }

    const float4 m = sGT[gi];
    const int conf = (biou < 0.5f) ? 0 : (sLab[gi] + 1);

    // encode: tolerance is 7.04, so plain f32 is fine here
    const float pcx = (pr.x + pr.z) * 0.5f;
    const float pcy = (pr.y + pr.w) * 0.5f;
    const float pw = pr.z - pr.x;
    const float ph = pr.w - pr.y;
    const float gcx = (m.x + m.z) * 0.5f;
    const float gcy = (m.y + m.w) * 0.5f;
    const float gw = m.z - m.x;
    const float gh = m.w - m.y;

    float4 loc;
    loc.x = (gcx - pcx) / (0.1f * pw);
    loc.y = (gcy - pcy) / (0.1f * ph);
    loc.z = logf(gw / pw) / 0.2f;
    loc.w = logf(gh / ph) / 0.2f;

    *reinterpret_cast<float4*>(out + ((size_t)b * NUM_PRIORS + p) * 4) = loc;
    out[(size_t)BATCH * NUM_PRIORS * 4 + (size_t)b * NUM_PRIORS + p] = (float)conf;
}

extern "C" void kernel_launch(void* const* d_in, const int* in_sizes, int n_in,
                              void* d_out, int out_size, void* d_ws, size_t ws_size,
                              hipStream_t stream) {
    const float* priors = (const float*)d_in[0];
    const float* gt_boxes = (const float*)d_in[1];
    const int* gt_labels = (const int*)d_in[2];
    float* out = (float*)d_out;
    u64* partials = (u64*)d_ws;  // [B][G][NCHUNK] u64 — fully written by kernel A

    dim3 grid1(NCHUNK, GNUM / GPB, BATCH);
    best_prior_partial<<<grid1, NBLK, 0, stream>>>(priors, gt_boxes, partials);

    dim3 grid2(NUM_PRIORS / NBLK, BATCH);
    match_kernel<<<grid2, NBLK, 0, stream>>>(priors, gt_boxes, gt_labels,
                                             partials, out);
}

// Round 7
// 115.680 us; speedup vs baseline: 1.0243x; 1.0243x over previous
//
#include <hip/hip_runtime.h>

#define NUM_PRIORS 65536
#define BATCH 8
#define GNUM 64
#define NBLK 256
#define GPB 4      // GTs per block in kernel A
#define NCHUNK 32  // prior chunks; 65536/32 = 2048 priors per block
#define PPT 8      // priors per thread in kernel A = 2048/256
#define PPB 2      // priors per thread in kernel B

typedef unsigned long long u64;
typedef unsigned int u32;

// ---------------------------------------------------------------------------
// Strict f32 IoU: `#pragma clang fp contract(off)` disables FMA contraction
// inside these helpers, making every op single-rounded in the reference op
// order -> bit-identical to the numpy strict-f32 reference regardless of
// surrounding codegen. (R3/R4 post-mortem: default -ffp-contract=fast fused
// the area/inter products in some codegen contexts, flipping one razor-edge
// argmax. __f*_rn intrinsics did NOT prevent this; inline asm did (R6 pass),
// but costs v_mov traffic on SGPR operands. Pragma keeps strictness with
// full codegen quality. If conf error 9.0 recurs -> revert to asm.)
// ---------------------------------------------------------------------------
__device__ inline float area_ref(const float4 bx) {
#pragma clang fp contract(off)
    return (bx.z - bx.x) * (bx.w - bx.y);
}

// ref op order: lt=max, rb=min, wh=max(rb-lt,0), inter=w*h,
// denom=(areaA+areaB)-inter, iou=inter/denom (IEEE divide, no fast-math).
__device__ inline float iou_ref(const float4 pr, float area_p,
                                const float4 gb, float area_g) {
#pragma clang fp contract(off)
    const float ltx = fmaxf(pr.x, gb.x);
    const float lty = fmaxf(pr.y, gb.y);
    const float rbx = fminf(pr.z, gb.z);
    const float rby = fminf(pr.w, gb.w);
    const float w = fmaxf(rbx - ltx, 0.0f);
    const float h = fmaxf(rby - lty, 0.0f);
    const float inter = w * h;
    const float denom = (area_p + area_g) - inter;
    return inter / denom;
}

__device__ inline u64 shfl_down_u64(u64 x, int off) {
    u32 lo = (u32)x, hi = (u32)(x >> 32);
    lo = __shfl_down(lo, off);
    hi = __shfl_down(hi, off);
    return ((u64)hi << 32) | lo;
}

// ---------------------------------------------------------------------------
// Kernel A: per (b, g, chunk) partial argmax over 2048 priors of IoU.
// Packed key (iou_bits<<32 | ~p): IoU >= 0 so fp32 bits are monotone as u32;
// ~p makes equal-IoU ties resolve to smallest p (argmax first-occurrence).
// Plain stores to partials — fully written, no pre-zeroing, no atomics.
// ---------------------------------------------------------------------------
__global__ __launch_bounds__(NBLK) void best_prior_partial(
    const float* __restrict__ priors,    // [P,4] corner
    const float* __restrict__ gt_boxes,  // [B,G,4] corner
    u64* __restrict__ partials)          // [B][G][NCHUNK]
{
    const int b = blockIdx.z;
    const int g0 = blockIdx.y * GPB;
    const int tid = threadIdx.x;

    float4 gb[GPB];
    float ag[GPB];
#pragma unroll
    for (int g = 0; g < GPB; ++g) {
        gb[g] = *reinterpret_cast<const float4*>(gt_boxes + (b * GNUM + g0 + g) * 4);
        ag[g] = area_ref(gb[g]);
    }

    u64 best[GPB];
#pragma unroll
    for (int g = 0; g < GPB; ++g) best[g] = 0ull;

    const int pbase = blockIdx.x * (NUM_PRIORS / NCHUNK) + tid;
#pragma unroll
    for (int i = 0; i < PPT; ++i) {
        const int p = pbase + i * NBLK;
        const float4 pr = *reinterpret_cast<const float4*>(priors + p * 4);
        const float area_p = area_ref(pr);
        const u64 notp = (u64)(~(u32)p);
#pragma unroll
        for (int g = 0; g < GPB; ++g) {
            const float iou = iou_ref(pr, area_p, gb[g], ag[g]);
            const u64 packed = ((u64)__float_as_uint(iou) << 32) | notp;
            best[g] = (packed > best[g]) ? packed : best[g];
        }
    }

    __shared__ u64 sRed[NBLK / 64][GPB];
    const int lane = tid & 63;
    const int wv = tid >> 6;
#pragma unroll
    for (int g = 0; g < GPB; ++g) {
        u64 v = best[g];
#pragma unroll
        for (int off = 32; off > 0; off >>= 1) {
            const u64 o = shfl_down_u64(v, off);
            v = (o > v) ? o : v;
        }
        if (lane == 0) sRed[wv][g] = v;
    }
    __syncthreads();
    if (tid < GPB) {
        u64 v = sRed[0][tid];
#pragma unroll
        for (int w = 1; w < NBLK / 64; ++w) {
            const u64 o = sRed[w][tid];
            v = (o > v) ? o : v;
        }
        partials[((size_t)b * GNUM + g0 + tid) * NCHUNK + blockIdx.x] = v;
    }
}

// ---------------------------------------------------------------------------
// Kernel B: per (b, p) for PPB priors per thread: strict-f32 argmax over g
// via packed u64 key (iou_bits<<6 | (63-g): tie -> smaller g = first
// occurrence); override via LDS scatter map (atomicMax -> last-g-wins = max g,
// numpy duplicate-scatter semantics); 0.5 threshold on the recovered f32 iou;
// SSD encode; write loc [B,P,4] + conf [B,P].
// ---------------------------------------------------------------------------
__global__ __launch_bounds__(NBLK) void match_kernel(
    const float* __restrict__ priors,    // [P,4]
    const float* __restrict__ gt_boxes,  // [B,G,4]
    const int* __restrict__ gt_labels,   // [B,G]
    const u64* __restrict__ partials,    // [B][G][NCHUNK]
    float* __restrict__ out)             // loc [B,P,4] then conf [B,P]
{
    const int b = blockIdx.y;
    const int p0 = blockIdx.x * (NBLK * PPB);
    const int tid = threadIdx.x;

    __shared__ float4 sGT[GNUM];
    __shared__ float sAG[GNUM];
    __shared__ int sLab[GNUM];
    __shared__ int sOvr[NBLK * PPB];

    int bpi_g = -1;
    if (tid < GNUM) {
        const float4 gbx = *reinterpret_cast<const float4*>(
            gt_boxes + (b * GNUM + tid) * 4);
        sGT[tid] = gbx;
        sAG[tid] = area_ref(gbx);
        sLab[tid] = gt_labels[b * GNUM + tid];
        const u64* pp = partials + ((size_t)b * GNUM + tid) * NCHUNK;
        u64 v = pp[0];
#pragma unroll
        for (int c = 1; c < NCHUNK; ++c) {
            const u64 o = pp[c];
            v = (o > v) ? o : v;
        }
        bpi_g = (int)(~(u32)v);
    }
#pragma unroll
    for (int i = 0; i < PPB; ++i) sOvr[tid + i * NBLK] = -1;
    __syncthreads();
    if (tid < GNUM) {
        const int rel = bpi_g - p0;
        if (rel >= 0 && rel < NBLK * PPB) atomicMax(&sOvr[rel], tid);
    }
    __syncthreads();

    float4 pr[PPB];
    float area_p[PPB];
    u64 key[PPB];
#pragma unroll
    for (int i = 0; i < PPB; ++i) {
        pr[i] = *reinterpret_cast<const float4*>(priors + (p0 + tid + i * NBLK) * 4);
        area_p[i] = area_ref(pr[i]);
        key[i] = 0ull;
    }

    for (int g = 0; g < GNUM; ++g) {
        const float4 gbx = sGT[g];
        const float agv = sAG[g];
        const u64 tie = (u64)(63 - g);
#pragma unroll
        for (int i = 0; i < PPB; ++i) {
            const float iou = iou_ref(pr[i], area_p[i], gbx, agv);
            const u64 k = ((u64)__float_as_uint(iou) << 6) | tie;
            key[i] = (k > key[i]) ? k : key[i];
        }
    }

#pragma unroll
    for (int i = 0; i < PPB; ++i) {
        const int p = p0 + tid + i * NBLK;
        int gi = 63 - (int)(key[i] & 63u);
        float biou = __uint_as_float((u32)(key[i] >> 6));
        const int ovr = sOvr[tid + i * NBLK];
        if (ovr >= 0) { gi = ovr; biou = 2.0f; }

        const float4 m = sGT[gi];
        const int conf = (biou < 0.5f) ? 0 : (sLab[gi] + 1);

        // encode: tolerance 7.04 -> plain f32 (contraction harmless here)
        const float pcx = (pr[i].x + pr[i].z) * 0.5f;
        const float pcy = (pr[i].y + pr[i].w) * 0.5f;
        const float pw = pr[i].z - pr[i].x;
        const float ph = pr[i].w - pr[i].y;
        const float gcx = (m.x + m.z) * 0.5f;
        const float gcy = (m.y + m.w) * 0.5f;
        const float gw = m.z - m.x;
        const float gh = m.w - m.y;

        float4 loc;
        loc.x = (gcx - pcx) / (0.1f * pw);
        loc.y = (gcy - pcy) / (0.1f * ph);
        loc.z = logf(gw / pw) / 0.2f;
        loc.w = logf(gh / ph) / 0.2f;

        *reinterpret_cast<float4*>(out + ((size_t)b * NUM_PRIORS + p) * 4) = loc;
        out[(size_t)BATCH * NUM_PRIORS * 4 + (size_t)b * NUM_PRIORS + p] = (float)conf;
    }
}

extern "C" void kernel_launch(void* const* d_in, const int* in_sizes, int n_in,
                              void* d_out, int out_size, void* d_ws, size_t ws_size,
                              hipStream_t stream) {
    const float* priors = (const float*)d_in[0];
    const float* gt_boxes = (const float*)d_in[1];
    const int* gt_labels = (const int*)d_in[2];
    float* out = (float*)d_out;
    u64* partials = (u64*)d_ws;  // [B][G][NCHUNK] u64 — fully written by kernel A

    dim3 grid1(NCHUNK, GNUM / GPB, BATCH);
    best_prior_partial<<<grid1, NBLK, 0, stream>>>(priors, gt_boxes, partials);

    dim3 grid2(NUM_PRIORS / (NBLK * PPB), BATCH);
    match_kernel<<<grid2, NBLK, 0, stream>>>(priors, gt_boxes, gt_labels,
                                             partials, out);
}